// Round 10
// baseline (626.597 us; speedup 1.0000x reference)
//
#include <hip/hip_runtime.h>

typedef __attribute__((ext_vector_type(8))) short s16x8;
typedef __attribute__((ext_vector_type(4))) float f32x4;
typedef unsigned short u16;
typedef unsigned char u8;

#define D_FEAT 128

__device__ __forceinline__ u16 f2bf(float f) {
    unsigned u = __builtin_bit_cast(unsigned, f);
    u = u + 0x7fffu + ((u >> 16) & 1u);   // RNE
    return (u16)(u >> 16);
}

// ---------------- x (fp32) -> bf16 ----------------
__global__ __launch_bounds__(256) void tobf16_kernel(const float4* __restrict__ X,
                                                     u16* __restrict__ out, int n4) {
    int i = blockIdx.x * 256 + threadIdx.x;
    if (i < n4) {
        float4 v = X[i];
        uint2 p;
        p.x = (unsigned)f2bf(v.x) | ((unsigned)f2bf(v.y) << 16);
        p.y = (unsigned)f2bf(v.z) | ((unsigned)f2bf(v.w) << 16);
        *(uint2*)(out + (size_t)i * 4) = p;
    }
}

// ---------------- CSR build ----------------
__global__ __launch_bounds__(256) void zero_kernel(int* __restrict__ p, int n) {
    int i = blockIdx.x * 256 + threadIdx.x;
    if (i < n) p[i] = 0;
}

__global__ __launch_bounds__(256) void count_kernel(const int* __restrict__ dst,
                                                    int* __restrict__ counts, int E) {
    int e = blockIdx.x * 256 + threadIdx.x;
    if (e < E) atomicAdd(&counts[dst[e]], 1);
}

__global__ __launch_bounds__(256) void scanA_kernel(const int* __restrict__ counts,
                                                    int* __restrict__ row_start,
                                                    int* __restrict__ bsum, int n) {
    __shared__ int wt[4];
    const int t = threadIdx.x, lane = t & 63, wid = t >> 6;
    const int i = blockIdx.x * 256 + t;
    int v = (i < n) ? counts[i] : 0;
    int s = v;
    #pragma unroll
    for (int off = 1; off < 64; off <<= 1) {
        int u = __shfl_up(s, off, 64);
        if (lane >= off) s += u;
    }
    if (lane == 63) wt[wid] = s;
    __syncthreads();
    int add = 0;
    #pragma unroll
    for (int w = 0; w < 4; ++w) add += (w < wid) ? wt[w] : 0;
    s += add;
    if (i < n) row_start[i + 1] = s;
    if (t == 255) bsum[blockIdx.x] = s;
}

__global__ __launch_bounds__(256) void scanB_kernel(const int* __restrict__ bsum,
                                                    int* __restrict__ bsum2, int m) {
    __shared__ int wt[4];
    const int t = threadIdx.x, lane = t & 63, wid = t >> 6;
    int v = (t < m) ? bsum[t] : 0;
    int s = v;
    #pragma unroll
    for (int off = 1; off < 64; off <<= 1) {
        int u = __shfl_up(s, off, 64);
        if (lane >= off) s += u;
    }
    if (lane == 63) wt[wid] = s;
    __syncthreads();
    int add = 0;
    #pragma unroll
    for (int w = 0; w < 4; ++w) add += (w < wid) ? wt[w] : 0;
    s += add;
    if (t < m) bsum2[t] = s - v;   // exclusive
}

__global__ __launch_bounds__(256) void scanC_kernel(int* __restrict__ row_start,
                                                    int* __restrict__ cursor,
                                                    const int* __restrict__ bsum2, int n) {
    const int i = blockIdx.x * 256 + threadIdx.x;
    if (i == 0) { row_start[0] = 0; cursor[0] = 0; }
    if (i < n) {
        int val = row_start[i + 1] + bsum2[blockIdx.x];
        row_start[i + 1] = val;
        if (i + 1 < n) cursor[i + 1] = val;
    }
}

__global__ __launch_bounds__(256) void scatter_kernel(const int* __restrict__ src,
                                                      const int* __restrict__ dst,
                                                      const int* __restrict__ eattr,
                                                      int* __restrict__ cursor,
                                                      unsigned* __restrict__ edges, int E) {
    int e = blockIdx.x * 256 + threadIdx.x;
    if (e < E) {
        unsigned s = (unsigned)src[e];
        unsigned code = (unsigned)(eattr[2 * e] * 3 + eattr[2 * e + 1]);
        int pos = atomicAdd(&cursor[dst[e]], 1);
        edges[pos] = s | (code << 16);
    }
}

// ---------------- weight prep: fp32 -> bf16 in MFMA FRAGMENT order ----------------
// chunk c (16B, 8 bf16) = frag for (t, kb, lane=(quad,m16)): c = (t*KB+kb)*64 + quad*16 + m16
// element j of chunk: W[k = kb*32+quad*8+j][n = t*16+m16]  (W row-major [K][Nc])
__global__ __launch_bounds__(256) void transpose_kernel(const float* __restrict__ W1_0,
                                                        const float* __restrict__ W2_0,
                                                        const float* __restrict__ W1_1,
                                                        const float* __restrict__ W2_1,
                                                        u16* __restrict__ out) {
    int mat = blockIdx.y;
    const float* s = (mat == 0) ? W1_0 : (mat == 1) ? W2_0 : (mat == 2) ? W1_1 : W2_1;
    int K  = (mat & 1) ? 256 : 128;    // W1: [128][256]; W2: [256][128]
    int Nc = 384 - K;
    int KB = K >> 5;                   // 4 or 8
    u16* d = out + mat * 32768;
    int idx = blockIdx.x * 256 + threadIdx.x;   // u16 index in [0, 32768)
    int j = idx & 7;
    int c = idx >> 3;
    int m16 = c & 15;
    int quad = (c >> 4) & 3;
    int rest = c >> 6;
    int kb = rest & (KB - 1);
    int t = rest / KB;
    int k = kb * 32 + quad * 8 + j;
    int n = t * 16 + m16;
    d[idx] = f2bf(s[k * Nc + n]);
}

__global__ __launch_bounds__(128) void emb_kernel(const float* __restrict__ ee1_0,
                                                  const float* __restrict__ ee2_0,
                                                  const float* __restrict__ ee1_1,
                                                  const float* __restrict__ ee2_1,
                                                  float* __restrict__ emb) {
    int code = blockIdx.x;
    int layer = blockIdx.y;
    int d = threadIdx.x;
    int a0 = code / 3, a1 = code - a0 * 3;
    const float* e1 = layer ? ee1_1 : ee1_0;
    const float* e2 = layer ? ee2_1 : ee2_0;
    emb[layer * 18 * 128 + code * 128 + d] = e1[a0 * 128 + d] + e2[a1 * 128 + d];
}

// ---------------- aggregation: one wave per node, 8-way batched bf16 gather ----------------
__global__ __launch_bounds__(256) void aggregate_kernel(const u16* __restrict__ X,
                                                        const int* __restrict__ row_start,
                                                        const unsigned* __restrict__ edges,
                                                        const float* __restrict__ emb,
                                                        u16* __restrict__ A, int N) {
    __shared__ float semb[18 * 128];
    for (int i = threadIdx.x; i < 18 * 128; i += 256) semb[i] = emb[i];
    __syncthreads();
    const int node = blockIdx.x * 4 + (threadIdx.x >> 6);
    const int lane = threadIdx.x & 63;
    if (node >= N) return;
    const int s = row_start[node], e = row_start[node + 1];
    const float2* sem2 = (const float2*)semb;
    const u16* xl = X + lane * 2;
    float a0 = 0.f, a1 = 0.f;
    int i = s;
    for (; i + 8 <= e; i += 8) {
        unsigned xv[8];
        float2 ev[8];
        unsigned p[8];
        #pragma unroll
        for (int j = 0; j < 8; ++j) p[j] = edges[i + j];
        #pragma unroll
        for (int j = 0; j < 8; ++j)
            xv[j] = *(const unsigned*)(xl + (p[j] & 0xFFFFu) * D_FEAT);
        #pragma unroll
        for (int j = 0; j < 8; ++j) ev[j] = sem2[(int)(p[j] >> 16) * 64 + lane];
        #pragma unroll
        for (int j = 0; j < 8; ++j) {
            a0 += __builtin_bit_cast(float, xv[j] << 16) + ev[j].x;
            a1 += __builtin_bit_cast(float, xv[j] & 0xFFFF0000u) + ev[j].y;
        }
    }
    for (; i < e; ++i) {
        unsigned p = edges[i];
        unsigned xv = *(const unsigned*)(xl + (p & 0xFFFFu) * D_FEAT);
        float2 ev = sem2[(int)(p >> 16) * 64 + lane];
        a0 += __builtin_bit_cast(float, xv << 16) + ev.x;
        a1 += __builtin_bit_cast(float, xv & 0xFFFF0000u) + ev.y;
    }
    unsigned out = (unsigned)f2bf(a0) | ((unsigned)f2bf(a1) << 16);
    *(unsigned*)(A + node * D_FEAT + lane * 2) = out;
}

// ---------------- fused MLP v2: weights persistent in LDS, no h round-trip ----------------
// gemm1 computed TRANSPOSED: h^T = W1^T @ x^T  (operand swap; frag bytes identical).
//   C1 layout: lane col = node(m16), rows = hcol(quad*4+r per tile t).
// gemm2 A-operand (lane=node m16, k=hcol octets) obtained from C1 by quad-only shuffles.
// Block 512 = 8 independent waves; W1+W2 frags staged once (conflict-free, chunk=src idx).
template <bool RELU2, bool OUTF32>
__global__ __launch_bounds__(512, 1) void mlp_kernel(const u16* __restrict__ A,
                                                     const u16* __restrict__ W1f,
                                                     const float* __restrict__ bias1,
                                                     const u16* __restrict__ W2f,
                                                     const float* __restrict__ bias2,
                                                     void* __restrict__ C, int M) {
    __shared__ __align__(16) u16 wbuf[65536];   // [0,32768): W1 frags; [32768,65536): W2 frags
    __shared__ float sbias[384];                // [0,256): b1; [256,384): b2
    const int tid = threadIdx.x;
    const int wave = tid >> 6;
    const int lane = tid & 63;
    const int m16 = lane & 15;
    const int quad = lane >> 4;

    {
        const uint4* g1 = (const uint4*)W1f;
        const uint4* g2 = (const uint4*)W2f;
        uint4* l = (uint4*)wbuf;
        #pragma unroll
        for (int i = 0; i < 8; ++i) {
            int s = i * 512 + tid;
            l[s] = g1[s];
            l[4096 + s] = g2[s];
        }
        if (tid < 256) sbias[tid] = bias1[tid];
        else if (tid < 384) sbias[tid] = bias2[tid - 256];
    }
    __syncthreads();

    const int nt = M >> 4;                       // 3125 row-tiles (M % 16 == 0)
    const int srcA = ((lane >> 4) & 1) * 32 + m16;
    const int srcB = srcA + 16;
    const bool sel = (lane & 32) != 0;

    for (int rt = blockIdx.x * 8 + wave; rt < nt; rt += gridDim.x * 8) {
        const int node = rt * 16 + m16;

        // x fragments (B-operand): lane(m16)=node, k-octet per quad
        s16x8 xf[4];
        #pragma unroll
        for (int kb = 0; kb < 4; ++kb)
            xf[kb] = *(const s16x8*)(A + node * 128 + kb * 32 + quad * 8);

        // gemm1^T: acc1[t] over 16 hcol-tiles
        f32x4 acc1[16];
        #pragma unroll
        for (int t = 0; t < 16; ++t) acc1[t] = f32x4{0, 0, 0, 0};
        #pragma unroll
        for (int kb = 0; kb < 4; ++kb) {
            #pragma unroll
            for (int t = 0; t < 16; ++t) {
                s16x8 wf = *(const s16x8*)(wbuf + ((t * 4 + kb) * 64 + lane) * 8);
                acc1[t] = __builtin_amdgcn_mfma_f32_16x16x32_bf16(wf, xf[kb], acc1[t], 0, 0, 0);
            }
        }

        // bias + relu + pack: p[t] = 4 bf16, hcols t*16+quad*4+{0..3}, node m16
        uint2 p[16];
        #pragma unroll
        for (int t = 0; t < 16; ++t) {
            float v0 = acc1[t][0] + sbias[t * 16 + quad * 4 + 0];
            float v1 = acc1[t][1] + sbias[t * 16 + quad * 4 + 1];
            float v2 = acc1[t][2] + sbias[t * 16 + quad * 4 + 2];
            float v3 = acc1[t][3] + sbias[t * 16 + quad * 4 + 3];
            v0 = v0 > 0.f ? v0 : 0.f;  v1 = v1 > 0.f ? v1 : 0.f;
            v2 = v2 > 0.f ? v2 : 0.f;  v3 = v3 > 0.f ? v3 : 0.f;
            p[t].x = (unsigned)f2bf(v0) | ((unsigned)f2bf(v1) << 16);
            p[t].y = (unsigned)f2bf(v2) | ((unsigned)f2bf(v3) << 16);
        }

        // gemm2: A = h-frags via quad shuffles, B = W2 frags from LDS
        f32x4 acc2[8];
        #pragma unroll
        for (int t = 0; t < 8; ++t) acc2[t] = f32x4{0, 0, 0, 0};
        #pragma unroll
        for (int kb = 0; kb < 8; ++kb) {
            uint2 ta = p[2 * kb], tb = p[2 * kb + 1];
            unsigned a0 = (unsigned)__shfl((int)ta.x, srcA, 64);
            unsigned a1 = (unsigned)__shfl((int)ta.y, srcA, 64);
            unsigned a2 = (unsigned)__shfl((int)ta.x, srcB, 64);
            unsigned a3 = (unsigned)__shfl((int)ta.y, srcB, 64);
            unsigned b0 = (unsigned)__shfl((int)tb.x, srcA, 64);
            unsigned b1 = (unsigned)__shfl((int)tb.y, srcA, 64);
            unsigned b2 = (unsigned)__shfl((int)tb.x, srcB, 64);
            unsigned b3 = (unsigned)__shfl((int)tb.y, srcB, 64);
            uint4 hfi;
            hfi.x = sel ? b0 : a0;
            hfi.y = sel ? b1 : a1;
            hfi.z = sel ? b2 : a2;
            hfi.w = sel ? b3 : a3;
            s16x8 hf = __builtin_bit_cast(s16x8, hfi);
            #pragma unroll
            for (int t = 0; t < 8; ++t) {
                s16x8 wf = *(const s16x8*)(wbuf + (4096 + (t * 8 + kb) * 64 + lane) * 8);
                acc2[t] = __builtin_amdgcn_mfma_f32_16x16x32_bf16(hf, wf, acc2[t], 0, 0, 0);
            }
        }

        // epilogue: C layout col=ocol(m16), row=node(quad*4+r)
        #pragma unroll
        for (int t = 0; t < 8; ++t) {
            const int col = t * 16 + m16;
            const float bv = sbias[256 + col];
            #pragma unroll
            for (int r = 0; r < 4; ++r) {
                const int row = rt * 16 + quad * 4 + r;
                float v = acc2[t][r] + bv;
                if (RELU2) v = v > 0.f ? v : 0.f;
                if (OUTF32) ((float*)C)[row * 128 + col] = v;
                else        ((u16*)C)[row * 128 + col] = f2bf(v);
            }
        }
    }
}

extern "C" void kernel_launch(void* const* d_in, const int* in_sizes, int n_in,
                              void* d_out, int out_size, void* d_ws, size_t ws_size,
                              hipStream_t stream) {
    const int N = in_sizes[0] / D_FEAT;     // 50000 (multiple of 16)
    const int E = in_sizes[1] / 2;          // 800000

    const float* x    = (const float*)d_in[0];
    const int* eidx   = (const int*)d_in[1];
    const int* eattr  = (const int*)d_in[2];
    const float* ee1_0 = (const float*)d_in[3];
    const float* ee2_0 = (const float*)d_in[4];
    const float* W1_0  = (const float*)d_in[5];
    const float* b1_0  = (const float*)d_in[6];
    const float* W2_0  = (const float*)d_in[7];
    const float* b2_0  = (const float*)d_in[8];
    const float* ee1_1 = (const float*)d_in[9];
    const float* ee2_1 = (const float*)d_in[10];
    const float* W1_1  = (const float*)d_in[11];
    const float* b1_1  = (const float*)d_in[12];
    const float* W2_1  = (const float*)d_in[13];
    const float* b2_1  = (const float*)d_in[14];

    // workspace (~16.68 MB)
    char* ws = (char*)d_ws;
    size_t off = 0;
    auto alloc = [&](size_t bytes) { size_t o = off; off = (off + bytes + 255) & ~(size_t)255; return o; };
    size_t o_rowstart = alloc((size_t)(N + 1) * 4);
    size_t o_cursor   = alloc((size_t)N * 4);
    size_t o_edges    = alloc((size_t)E * 4);
    size_t o_bsum     = alloc(1024);
    size_t o_bsum2    = alloc(1024);
    size_t o_emb      = alloc(2 * 18 * 128 * 4);
    size_t o_wt       = alloc(4 * 32768 * 2);
    size_t o_aa       = alloc((size_t)N * D_FEAT * 2);

    int*      row_start = (int*)(ws + o_rowstart);
    int*      cursor    = (int*)(ws + o_cursor);   // doubles as counts
    unsigned* edges     = (unsigned*)(ws + o_edges);
    int*      bsum      = (int*)(ws + o_bsum);
    int*      bsum2     = (int*)(ws + o_bsum2);
    float*    emb       = (float*)(ws + o_emb);
    u16*      W1t_0     = (u16*)(ws + o_wt);       // frag-order
    u16*      W2t_0     = W1t_0 + 32768;
    u16*      W1t_1     = W2t_0 + 32768;
    u16*      W2t_1     = W1t_1 + 32768;
    u16*      AA        = (u16*)(ws + o_aa);

    // d_out (fp32, 25.6 MB) staging: front = X2 (bf16 L0 output), back = xb (bf16 x)
    u16* X2 = (u16*)d_out;
    u16* xb = (u16*)d_out + (size_t)N * D_FEAT;

    const int Eb = (E + 255) / 256;
    const int Nb = (N + 255) / 256;
    const int aggB = (N + 3) / 4;
    const int n4 = N * D_FEAT / 4;

    tobf16_kernel<<<(n4 + 255) / 256, 256, 0, stream>>>((const float4*)x, xb, n4);

    // CSR build
    zero_kernel<<<Nb, 256, 0, stream>>>(cursor, N);
    count_kernel<<<Eb, 256, 0, stream>>>(eidx + E, cursor, E);
    scanA_kernel<<<Nb, 256, 0, stream>>>(cursor, row_start, bsum, N);
    scanB_kernel<<<1, 256, 0, stream>>>(bsum, bsum2, Nb);
    scanC_kernel<<<Nb, 256, 0, stream>>>(row_start, cursor, bsum2, N);
    scatter_kernel<<<Eb, 256, 0, stream>>>(eidx, eidx + E, eattr, cursor, edges, E);

    // prep
    emb_kernel<<<dim3(18, 2), 128, 0, stream>>>(ee1_0, ee2_0, ee1_1, ee2_1, emb);
    transpose_kernel<<<dim3(128, 4), 256, 0, stream>>>(W1_0, W2_0, W1_1, W2_1, W1t_0);

    // layer 0: xb -> AA -> X2
    aggregate_kernel<<<aggB, 256, 0, stream>>>(xb, row_start, edges, emb, AA, N);
    mlp_kernel<true, false><<<256, 512, 0, stream>>>(AA, W1t_0, b1_0, W2t_0, b2_0, X2, N);

    // layer 1: X2 -> AA -> d_out (fp32)
    aggregate_kernel<<<aggB, 256, 0, stream>>>(X2, row_start, edges, emb + 18 * 128, AA, N);
    mlp_kernel<false, true><<<256, 512, 0, stream>>>(AA, W1t_1, b1_1, W2t_1, b2_1, d_out, N);
}

// Round 11
// 623.123 us; speedup vs baseline: 1.0056x; 1.0056x over previous
//
#include <hip/hip_runtime.h>

typedef __attribute__((ext_vector_type(8))) short s16x8;
typedef __attribute__((ext_vector_type(4))) float f32x4;
typedef unsigned short u16;
typedef unsigned char u8;

#define D_FEAT 128

__device__ __forceinline__ u16 f2bf(float f) {
    unsigned u = __builtin_bit_cast(unsigned, f);
    u = u + 0x7fffu + ((u >> 16) & 1u);   // RNE
    return (u16)(u >> 16);
}

// ---------------- x (fp32) -> bf16 ----------------
__global__ __launch_bounds__(256) void tobf16_kernel(const float4* __restrict__ X,
                                                     u16* __restrict__ out, int n4) {
    int i = blockIdx.x * 256 + threadIdx.x;
    if (i < n4) {
        float4 v = X[i];
        uint2 p;
        p.x = (unsigned)f2bf(v.x) | ((unsigned)f2bf(v.y) << 16);
        p.y = (unsigned)f2bf(v.z) | ((unsigned)f2bf(v.w) << 16);
        *(uint2*)(out + (size_t)i * 4) = p;
    }
}

// ---------------- CSR build ----------------
__global__ __launch_bounds__(256) void zero_kernel(int* __restrict__ p, int n) {
    int i = blockIdx.x * 256 + threadIdx.x;
    if (i < n) p[i] = 0;
}

__global__ __launch_bounds__(256) void count_kernel(const int* __restrict__ dst,
                                                    int* __restrict__ counts, int E) {
    int e = blockIdx.x * 256 + threadIdx.x;
    if (e < E) atomicAdd(&counts[dst[e]], 1);
}

__global__ __launch_bounds__(256) void scanA_kernel(const int* __restrict__ counts,
                                                    int* __restrict__ row_start,
                                                    int* __restrict__ bsum, int n) {
    __shared__ int wt[4];
    const int t = threadIdx.x, lane = t & 63, wid = t >> 6;
    const int i = blockIdx.x * 256 + t;
    int v = (i < n) ? counts[i] : 0;
    int s = v;
    #pragma unroll
    for (int off = 1; off < 64; off <<= 1) {
        int u = __shfl_up(s, off, 64);
        if (lane >= off) s += u;
    }
    if (lane == 63) wt[wid] = s;
    __syncthreads();
    int add = 0;
    #pragma unroll
    for (int w = 0; w < 4; ++w) add += (w < wid) ? wt[w] : 0;
    s += add;
    if (i < n) row_start[i + 1] = s;
    if (t == 255) bsum[blockIdx.x] = s;
}

__global__ __launch_bounds__(256) void scanB_kernel(const int* __restrict__ bsum,
                                                    int* __restrict__ bsum2, int m) {
    __shared__ int wt[4];
    const int t = threadIdx.x, lane = t & 63, wid = t >> 6;
    int v = (t < m) ? bsum[t] : 0;
    int s = v;
    #pragma unroll
    for (int off = 1; off < 64; off <<= 1) {
        int u = __shfl_up(s, off, 64);
        if (lane >= off) s += u;
    }
    if (lane == 63) wt[wid] = s;
    __syncthreads();
    int add = 0;
    #pragma unroll
    for (int w = 0; w < 4; ++w) add += (w < wid) ? wt[w] : 0;
    s += add;
    if (t < m) bsum2[t] = s - v;   // exclusive
}

__global__ __launch_bounds__(256) void scanC_kernel(int* __restrict__ row_start,
                                                    int* __restrict__ cursor,
                                                    const int* __restrict__ bsum2, int n) {
    const int i = blockIdx.x * 256 + threadIdx.x;
    if (i == 0) { row_start[0] = 0; cursor[0] = 0; }
    if (i < n) {
        int val = row_start[i + 1] + bsum2[blockIdx.x];
        row_start[i + 1] = val;
        if (i + 1 < n) cursor[i + 1] = val;
    }
}

__global__ __launch_bounds__(256) void scatter_kernel(const int* __restrict__ src,
                                                      const int* __restrict__ dst,
                                                      const int* __restrict__ eattr,
                                                      int* __restrict__ cursor,
                                                      unsigned* __restrict__ edges, int E) {
    int e = blockIdx.x * 256 + threadIdx.x;
    if (e < E) {
        unsigned s = (unsigned)src[e];
        unsigned code = (unsigned)(eattr[2 * e] * 3 + eattr[2 * e + 1]);
        int pos = atomicAdd(&cursor[dst[e]], 1);
        edges[pos] = s | (code << 16);
    }
}

// ---------------- weight prep: fp32 -> bf16 in MFMA FRAGMENT order ----------------
// chunk c (16B, 8 bf16) = frag for (t, kb, lane=(quad,m16)): c = (t*KB+kb)*64 + quad*16 + m16
// element j of chunk: W[k = kb*32+quad*8+j][n = t*16+m16]  (W row-major [K][Nc])
__global__ __launch_bounds__(256) void transpose_kernel(const float* __restrict__ W1_0,
                                                        const float* __restrict__ W2_0,
                                                        const float* __restrict__ W1_1,
                                                        const float* __restrict__ W2_1,
                                                        u16* __restrict__ out) {
    int mat = blockIdx.y;
    const float* s = (mat == 0) ? W1_0 : (mat == 1) ? W2_0 : (mat == 2) ? W1_1 : W2_1;
    int K  = (mat & 1) ? 256 : 128;    // W1: [128][256]; W2: [256][128]
    int Nc = 384 - K;
    int KB = K >> 5;                   // 4 or 8
    u16* d = out + mat * 32768;
    int idx = blockIdx.x * 256 + threadIdx.x;   // u16 index in [0, 32768)
    int j = idx & 7;
    int c = idx >> 3;
    int m16 = c & 15;
    int quad = (c >> 4) & 3;
    int rest = c >> 6;
    int kb = rest & (KB - 1);
    int t = rest / KB;
    int k = kb * 32 + quad * 8 + j;
    int n = t * 16 + m16;
    d[idx] = f2bf(s[k * Nc + n]);
}

__global__ __launch_bounds__(128) void emb_kernel(const float* __restrict__ ee1_0,
                                                  const float* __restrict__ ee2_0,
                                                  const float* __restrict__ ee1_1,
                                                  const float* __restrict__ ee2_1,
                                                  float* __restrict__ emb) {
    int code = blockIdx.x;
    int layer = blockIdx.y;
    int d = threadIdx.x;
    int a0 = code / 3, a1 = code - a0 * 3;
    const float* e1 = layer ? ee1_1 : ee1_0;
    const float* e2 = layer ? ee2_1 : ee2_0;
    emb[layer * 18 * 128 + code * 128 + d] = e1[a0 * 128 + d] + e2[a1 * 128 + d];
}

// ---------------- aggregation: one wave per node, 8-way batched bf16 gather ----------------
__global__ __launch_bounds__(256) void aggregate_kernel(const u16* __restrict__ X,
                                                        const int* __restrict__ row_start,
                                                        const unsigned* __restrict__ edges,
                                                        const float* __restrict__ emb,
                                                        u16* __restrict__ A, int N) {
    __shared__ float semb[18 * 128];
    for (int i = threadIdx.x; i < 18 * 128; i += 256) semb[i] = emb[i];
    __syncthreads();
    const int node = blockIdx.x * 4 + (threadIdx.x >> 6);
    const int lane = threadIdx.x & 63;
    if (node >= N) return;
    const int s = row_start[node], e = row_start[node + 1];
    const float2* sem2 = (const float2*)semb;
    const u16* xl = X + lane * 2;
    float a0 = 0.f, a1 = 0.f;
    int i = s;
    for (; i + 8 <= e; i += 8) {
        unsigned xv[8];
        float2 ev[8];
        unsigned p[8];
        #pragma unroll
        for (int j = 0; j < 8; ++j) p[j] = edges[i + j];
        #pragma unroll
        for (int j = 0; j < 8; ++j)
            xv[j] = *(const unsigned*)(xl + (p[j] & 0xFFFFu) * D_FEAT);
        #pragma unroll
        for (int j = 0; j < 8; ++j) ev[j] = sem2[(int)(p[j] >> 16) * 64 + lane];
        #pragma unroll
        for (int j = 0; j < 8; ++j) {
            a0 += __builtin_bit_cast(float, xv[j] << 16) + ev[j].x;
            a1 += __builtin_bit_cast(float, xv[j] & 0xFFFF0000u) + ev[j].y;
        }
    }
    for (; i < e; ++i) {
        unsigned p = edges[i];
        unsigned xv = *(const unsigned*)(xl + (p & 0xFFFFu) * D_FEAT);
        float2 ev = sem2[(int)(p >> 16) * 64 + lane];
        a0 += __builtin_bit_cast(float, xv << 16) + ev.x;
        a1 += __builtin_bit_cast(float, xv & 0xFFFF0000u) + ev.y;
    }
    unsigned out = (unsigned)f2bf(a0) | ((unsigned)f2bf(a1) << 16);
    *(unsigned*)(A + node * D_FEAT + lane * 2) = out;
}

// ---------------- fused MLP v3: persistent LDS weights, fused kb2 loop, no spills ----------------
// gemm1 transposed (h^T = W1^T @ x^T, operand swap); gemm2 A-frags via quad-only shuffles.
// Per kb2 step: only c0,c1 (+acc2[8], xf[4]) live -> ~90 VGPRs, no scratch.
template <bool RELU2, bool OUTF32>
__global__ __launch_bounds__(512, 1) void mlp_kernel(const u16* __restrict__ A,
                                                     const u16* __restrict__ W1f,
                                                     const float* __restrict__ bias1,
                                                     const u16* __restrict__ W2f,
                                                     const float* __restrict__ bias2,
                                                     void* __restrict__ C, int M) {
    __shared__ __align__(16) u16 wbuf[65536];   // [0,32768): W1 frags; [32768,65536): W2 frags
    __shared__ float sbias[384];                // [0,256): b1; [256,384): b2
    const int tid = threadIdx.x;
    const int wave = tid >> 6;
    const int lane = tid & 63;
    const int m16 = lane & 15;
    const int quad = lane >> 4;

    {
        const uint4* g1 = (const uint4*)W1f;
        const uint4* g2 = (const uint4*)W2f;
        uint4* l = (uint4*)wbuf;
        #pragma unroll
        for (int i = 0; i < 8; ++i) {
            int s = i * 512 + tid;
            l[s] = g1[s];
            l[4096 + s] = g2[s];
        }
        if (tid < 256) sbias[tid] = bias1[tid];
        else if (tid < 384) sbias[tid] = bias2[tid - 256];
    }
    __syncthreads();

    const int nt = M >> 4;                       // 3125 row-tiles (M % 16 == 0)
    const int srcA = ((lane >> 4) & 1) * 32 + m16;
    const int srcB = srcA + 16;
    const bool sel = (lane & 32) != 0;

    for (int rt = blockIdx.x * 8 + wave; rt < nt; rt += gridDim.x * 8) {
        const int node = rt * 16 + m16;

        // x fragments (B-operand of gemm1^T): lane(m16)=node, k-octet per quad
        s16x8 xf[4];
        #pragma unroll
        for (int kb = 0; kb < 4; ++kb)
            xf[kb] = *(const s16x8*)(A + node * 128 + kb * 32 + quad * 8);

        f32x4 acc2[8];
        #pragma unroll
        for (int t = 0; t < 8; ++t) acc2[t] = f32x4{0, 0, 0, 0};

        #pragma unroll
        for (int kb2 = 0; kb2 < 8; ++kb2) {
            const int t0 = 2 * kb2, t1 = 2 * kb2 + 1;

            // gemm1^T for hcol tiles t0,t1 (8 MFMAs)
            f32x4 c0 = f32x4{0, 0, 0, 0}, c1 = f32x4{0, 0, 0, 0};
            #pragma unroll
            for (int kb = 0; kb < 4; ++kb) {
                s16x8 wf0 = *(const s16x8*)(wbuf + ((t0 * 4 + kb) * 64 + lane) * 8);
                c0 = __builtin_amdgcn_mfma_f32_16x16x32_bf16(wf0, xf[kb], c0, 0, 0, 0);
            }
            #pragma unroll
            for (int kb = 0; kb < 4; ++kb) {
                s16x8 wf1 = *(const s16x8*)(wbuf + ((t1 * 4 + kb) * 64 + lane) * 8);
                c1 = __builtin_amdgcn_mfma_f32_16x16x32_bf16(wf1, xf[kb], c1, 0, 0, 0);
            }

            // bias + relu + pack (hcols t*16+quad*4+{0..3}, node=m16)
            uint2 ta, tb;
            {
                float v0 = c0[0] + sbias[t0 * 16 + quad * 4 + 0];
                float v1 = c0[1] + sbias[t0 * 16 + quad * 4 + 1];
                float v2 = c0[2] + sbias[t0 * 16 + quad * 4 + 2];
                float v3 = c0[3] + sbias[t0 * 16 + quad * 4 + 3];
                v0 = v0 > 0.f ? v0 : 0.f;  v1 = v1 > 0.f ? v1 : 0.f;
                v2 = v2 > 0.f ? v2 : 0.f;  v3 = v3 > 0.f ? v3 : 0.f;
                ta.x = (unsigned)f2bf(v0) | ((unsigned)f2bf(v1) << 16);
                ta.y = (unsigned)f2bf(v2) | ((unsigned)f2bf(v3) << 16);
            }
            {
                float v0 = c1[0] + sbias[t1 * 16 + quad * 4 + 0];
                float v1 = c1[1] + sbias[t1 * 16 + quad * 4 + 1];
                float v2 = c1[2] + sbias[t1 * 16 + quad * 4 + 2];
                float v3 = c1[3] + sbias[t1 * 16 + quad * 4 + 3];
                v0 = v0 > 0.f ? v0 : 0.f;  v1 = v1 > 0.f ? v1 : 0.f;
                v2 = v2 > 0.f ? v2 : 0.f;  v3 = v3 > 0.f ? v3 : 0.f;
                tb.x = (unsigned)f2bf(v0) | ((unsigned)f2bf(v1) << 16);
                tb.y = (unsigned)f2bf(v2) | ((unsigned)f2bf(v3) << 16);
            }

            // quad-only shuffles -> gemm2 A-fragment (k = kb2*32 + quad*8 + {0..7})
            unsigned a0 = (unsigned)__shfl((int)ta.x, srcA, 64);
            unsigned a1 = (unsigned)__shfl((int)ta.y, srcA, 64);
            unsigned a2 = (unsigned)__shfl((int)ta.x, srcB, 64);
            unsigned a3 = (unsigned)__shfl((int)ta.y, srcB, 64);
            unsigned b0 = (unsigned)__shfl((int)tb.x, srcA, 64);
            unsigned b1 = (unsigned)__shfl((int)tb.y, srcA, 64);
            unsigned b2 = (unsigned)__shfl((int)tb.x, srcB, 64);
            unsigned b3 = (unsigned)__shfl((int)tb.y, srcB, 64);
            uint4 hfi;
            hfi.x = sel ? b0 : a0;
            hfi.y = sel ? b1 : a1;
            hfi.z = sel ? b2 : a2;
            hfi.w = sel ? b3 : a3;
            s16x8 hf = __builtin_bit_cast(s16x8, hfi);

            // gemm2 k-step kb2 (8 MFMAs)
            #pragma unroll
            for (int t = 0; t < 8; ++t) {
                s16x8 wf2 = *(const s16x8*)(wbuf + (4096 + (t * 8 + kb2) * 64 + lane) * 8);
                acc2[t] = __builtin_amdgcn_mfma_f32_16x16x32_bf16(hf, wf2, acc2[t], 0, 0, 0);
            }
        }

        // epilogue: C layout col=ocol(m16), row=node(quad*4+r)
        #pragma unroll
        for (int t = 0; t < 8; ++t) {
            const int col = t * 16 + m16;
            const float bv = sbias[256 + col];
            #pragma unroll
            for (int r = 0; r < 4; ++r) {
                const int row = rt * 16 + quad * 4 + r;
                float v = acc2[t][r] + bv;
                if (RELU2) v = v > 0.f ? v : 0.f;
                if (OUTF32) ((float*)C)[row * 128 + col] = v;
                else        ((u16*)C)[row * 128 + col] = f2bf(v);
            }
        }
    }
}

extern "C" void kernel_launch(void* const* d_in, const int* in_sizes, int n_in,
                              void* d_out, int out_size, void* d_ws, size_t ws_size,
                              hipStream_t stream) {
    const int N = in_sizes[0] / D_FEAT;     // 50000 (multiple of 16)
    const int E = in_sizes[1] / 2;          // 800000

    const float* x    = (const float*)d_in[0];
    const int* eidx   = (const int*)d_in[1];
    const int* eattr  = (const int*)d_in[2];
    const float* ee1_0 = (const float*)d_in[3];
    const float* ee2_0 = (const float*)d_in[4];
    const float* W1_0  = (const float*)d_in[5];
    const float* b1_0  = (const float*)d_in[6];
    const float* W2_0  = (const float*)d_in[7];
    const float* b2_0  = (const float*)d_in[8];
    const float* ee1_1 = (const float*)d_in[9];
    const float* ee2_1 = (const float*)d_in[10];
    const float* W1_1  = (const float*)d_in[11];
    const float* b1_1  = (const float*)d_in[12];
    const float* W2_1  = (const float*)d_in[13];
    const float* b2_1  = (const float*)d_in[14];

    // workspace (~16.68 MB)
    char* ws = (char*)d_ws;
    size_t off = 0;
    auto alloc = [&](size_t bytes) { size_t o = off; off = (off + bytes + 255) & ~(size_t)255; return o; };
    size_t o_rowstart = alloc((size_t)(N + 1) * 4);
    size_t o_cursor   = alloc((size_t)N * 4);
    size_t o_edges    = alloc((size_t)E * 4);
    size_t o_bsum     = alloc(1024);
    size_t o_bsum2    = alloc(1024);
    size_t o_emb      = alloc(2 * 18 * 128 * 4);
    size_t o_wt       = alloc(4 * 32768 * 2);
    size_t o_aa       = alloc((size_t)N * D_FEAT * 2);

    int*      row_start = (int*)(ws + o_rowstart);
    int*      cursor    = (int*)(ws + o_cursor);   // doubles as counts
    unsigned* edges     = (unsigned*)(ws + o_edges);
    int*      bsum      = (int*)(ws + o_bsum);
    int*      bsum2     = (int*)(ws + o_bsum2);
    float*    emb       = (float*)(ws + o_emb);
    u16*      W1t_0     = (u16*)(ws + o_wt);       // frag-order
    u16*      W2t_0     = W1t_0 + 32768;
    u16*      W1t_1     = W2t_0 + 32768;
    u16*      W2t_1     = W1t_1 + 32768;
    u16*      AA        = (u16*)(ws + o_aa);

    // d_out (fp32, 25.6 MB) staging: front = X2 (bf16 L0 output), back = xb (bf16 x)
    u16* X2 = (u16*)d_out;
    u16* xb = (u16*)d_out + (size_t)N * D_FEAT;

    const int Eb = (E + 255) / 256;
    const int Nb = (N + 255) / 256;
    const int aggB = (N + 3) / 4;
    const int n4 = N * D_FEAT / 4;

    tobf16_kernel<<<(n4 + 255) / 256, 256, 0, stream>>>((const float4*)x, xb, n4);

    // CSR build
    zero_kernel<<<Nb, 256, 0, stream>>>(cursor, N);
    count_kernel<<<Eb, 256, 0, stream>>>(eidx + E, cursor, E);
    scanA_kernel<<<Nb, 256, 0, stream>>>(cursor, row_start, bsum, N);
    scanB_kernel<<<1, 256, 0, stream>>>(bsum, bsum2, Nb);
    scanC_kernel<<<Nb, 256, 0, stream>>>(row_start, cursor, bsum2, N);
    scatter_kernel<<<Eb, 256, 0, stream>>>(eidx, eidx + E, eattr, cursor, edges, E);

    // prep
    emb_kernel<<<dim3(18, 2), 128, 0, stream>>>(ee1_0, ee2_0, ee1_1, ee2_1, emb);
    transpose_kernel<<<dim3(128, 4), 256, 0, stream>>>(W1_0, W2_0, W1_1, W2_1, W1t_0);

    // layer 0: xb -> AA -> X2
    aggregate_kernel<<<aggB, 256, 0, stream>>>(xb, row_start, edges, emb, AA, N);
    mlp_kernel<true, false><<<256, 512, 0, stream>>>(AA, W1t_0, b1_0, W2t_0, b2_0, X2, N);

    // layer 1: X2 -> AA -> d_out (fp32)
    aggregate_kernel<<<aggB, 256, 0, stream>>>(X2, row_start, edges, emb + 18 * 128, AA, N);
    mlp_kernel<false, true><<<256, 512, 0, stream>>>(AA, W1t_1, b1_1, W2t_1, b2_1, d_out, N);
}